// Round 13
// baseline (224.636 us; speedup 1.0000x reference)
//
#include <hip/hip_runtime.h>
#include <hip/hip_bf16.h>

#define N_SRC 50000
#define N_DST 50000
#define NEDGE 800000
#define IND   128
#define HEADS 4
#define CDIM  64
#define HC    256   // HEADS*CDIM
#define KTOT  512   // HEADS*IND — final GEMM K
#define MAXDEG 96   // max in-degree; Binomial(800k,1/50k) max ~40, P(>96)~1e-22
#define HIST_GPB 256     // hist blocks per dst-range group
#define NB_HIST2 2048    // 8 groups * HIST_GPB
#define DPG 6250         // dst nodes per group (N_DST/8)
#define NB_G16 3125      // GEMV blocks per side (16 nodes/block)
#define NB_CAST 3125     // x_src f32->f16 cast blocks
// R4 LESSON: shared tail counters fatal (~500ns serialized same-address atomic).
// R5/R6/R8 LESSON: hist ~55-62 us across 5 structures — the transaction floor.
// R11: co-dispatching low-VGPR BW work (GEMV/cast) under the hist is ~free.
// R12 LESSON: LDS-fusing the z GEMM into aggregate is NEUTRAL-to-WORSE —
// idle waves in the MFMA phase + per-block WfT re-staging eat the z savings.
// R6 LESSON: static __shared__ charges EVERY block in a multi-role kernel.
// R7 LESSON: per-wave re-streamed weights = L2 bound; stage in LDS once/block.
// R9 LESSON: random-gather kernels sit at the per-XCD COMPULSORY floor
// (FETCH = table x 8 XCDs; MLP-insensitive) -> only shrinking the table helps.
// R10: x-space aggregation (12.8 MB table) + post-GEMM; absmax 0.0039.
// R13 (this round): NT hints on ALL big-kernel rider traffic (GEMV/cast) so
// the 64 MB single-use x stream doesn't evict the hist's L2-resident col2.

typedef _Float16 half8  __attribute__((ext_vector_type(8)));
typedef _Float16 half2t __attribute__((ext_vector_type(2)));
typedef float    f32x4  __attribute__((ext_vector_type(4)));
typedef int      i32x4  __attribute__((ext_vector_type(4)));

static __device__ __forceinline__ unsigned int pack2h(float a, float b) {
    union { half2t h; unsigned int u; } v;
    v.h[0] = (_Float16)a; v.h[1] = (_Float16)b;
    return v.u;
}
static __device__ __forceinline__ half2t bits2h(unsigned int u) {
    union { unsigned int u; half2t h; } v; v.u = u; return v.h;
}

// ---------------------------------------------------------------------------
// prep0: [0,196) zero deg; [196,198) fold W_dst·att_dst -> WdA[k*4+h];
// [198,200) fold W_src·att_src -> WsA; [200,328) WfT[c][h*128+k] f16.
__global__ void prep0_kernel(const float* __restrict__ Wdst,
                             const float* __restrict__ att_d,
                             float* __restrict__ WdA,
                             const float* __restrict__ Wsrc,
                             const float* __restrict__ att_s,
                             float* __restrict__ WsA,
                             _Float16* __restrict__ WfT,
                             int* __restrict__ deg) {
    int b = blockIdx.x, tid = threadIdx.x;
    if (b < 196) {
        int i = b * 256 + tid;
        if (i < N_DST) deg[i] = 0;
    } else if (b < 198) {
        int id = (b - 196) * 256 + tid;   // 0..511
        int k = id >> 2, h = id & 3;
        float acc = 0.f;
        for (int c = 0; c < CDIM; ++c)
            acc += Wdst[k * HC + h * CDIM + c] * att_d[h * CDIM + c];
        WdA[id] = acc;   // id == k*4+h
    } else if (b < 200) {
        int id = (b - 198) * 256 + tid;   // 0..511
        int k = id >> 2, h = id & 3;
        float acc = 0.f;
        for (int c = 0; c < CDIM; ++c)
            acc += Wsrc[k * HC + h * CDIM + c] * att_s[h * CDIM + c];
        WsA[id] = acc;
    } else {
        // WfT[c][hk]: c=0..63 out col, hk = h*128+k.  32768 elems.
        int idx = (b - 200) * 256 + tid;
        int c = idx >> 9, hk = idx & 511;
        int h = hk >> 7, k = hk & 127;
        WfT[idx] = (_Float16)Wsrc[k * HC + h * CDIM + c];
    }
}

// ---------------------------------------------------------------------------
// big (R11 + R13 NT riders): hist + GEMVs + cast co-dispatched.  hist ranks
// FIRST (transaction-bound, leaves BW/VALU idle); GEMV + cast (pure BW, VGPR
// 12-24) fill the idle pipes under it.  ALL rider traffic is non-temporal so
// it cannot evict the hist's L2-resident col2/deg slices (the R2 mechanism).
__global__ __launch_bounds__(256) void big_kernel(
        const float* __restrict__ x_dst, const float* __restrict__ WdA,
        float* __restrict__ a_d,
        const float* __restrict__ x_src, const float* __restrict__ WsA,
        float* __restrict__ a_s,
        _Float16* __restrict__ xh,
        const int* __restrict__ src, const int* __restrict__ dst,
        int* __restrict__ deg, int* __restrict__ col2) {
    int b = blockIdx.x, tid = threadIdx.x;
    if (b < NB_HIST2) {
        int g  = b & 7;            // XCD-affine group
        int bg = b >> 3;           // 0..HIST_GPB-1 within group
        int lo = g * DPG, hi = lo + DPG;
        #pragma unroll 1
        for (int it = 0; it < 4; ++it) {
            int base = ((it * HIST_GPB + bg) << 10) + (tid << 2);
            if (base >= NEDGE) break;   // monotone in it; NEDGE%4==0, no straddle
            i32x4 dv = __builtin_nontemporal_load((const i32x4*)(dst + base));
            i32x4 sv = __builtin_nontemporal_load((const i32x4*)(src + base));
            #pragma unroll
            for (int j = 0; j < 4; ++j) {
                int d = dv[j];
                if (d >= lo && d < hi) {
                    int r = atomicAdd(&deg[d], 1);
                    if (r < MAXDEG) col2[d * MAXDEG + r] = sv[j];
                }
            }
        }
        return;
    }
    int rank = b - NB_HIST2;
    if (rank < 2 * NB_G16) {
        // ---- GEMV: 16 nodes/block (wave w: 4 nodes), folded 128x4 table ----
        const float* xbase; const float4* wa; float* outp; int which;
        if (rank < NB_G16) { xbase = x_dst; wa = (const float4*)WdA; outp = a_d; which = rank; }
        else               { xbase = x_src; wa = (const float4*)WsA; outp = a_s; which = rank - NB_G16; }
        int w = tid >> 6, lane = tid & 63;
        float4 wa0 = wa[lane], wa1 = wa[lane + 64];   // hoisted across 4 nodes
        int n0 = which * 16 + w * 4;
        #pragma unroll
        for (int p = 0; p < 4; ++p) {
            int n = n0 + p;
            const float* xp = xbase + (size_t)n * IND;
            float x0 = __builtin_nontemporal_load(xp + lane);
            float x1 = __builtin_nontemporal_load(xp + lane + 64);
            float p0 = x0 * wa0.x + x1 * wa1.x;
            float p1 = x0 * wa0.y + x1 * wa1.y;
            float p2 = x0 * wa0.z + x1 * wa1.z;
            float p3 = x0 * wa0.w + x1 * wa1.w;
            for (int off = 32; off >= 1; off >>= 1) {
                p0 += __shfl_xor(p0, off, 64);
                p1 += __shfl_xor(p1, off, 64);
                p2 += __shfl_xor(p2, off, 64);
                p3 += __shfl_xor(p3, off, 64);
            }
            if (lane == 0) {
                __builtin_nontemporal_store(p0, outp + n * 4 + 0);
                __builtin_nontemporal_store(p1, outp + n * 4 + 1);
                __builtin_nontemporal_store(p2, outp + n * 4 + 2);
                __builtin_nontemporal_store(p3, outp + n * 4 + 3);
            }
        }
    } else {
        // ---- cast x_src -> xh f16, 8 elems/thread, fully coalesced, NT ----
        int e = (rank - 2 * NB_G16) * 256 + tid;   // 0..799999, *8 elems
        const f32x4* xp = (const f32x4*)(x_src + (size_t)e * 8);
        f32x4 u0 = __builtin_nontemporal_load(xp);
        f32x4 u1 = __builtin_nontemporal_load(xp + 1);
        half8 v;
        v[0] = (_Float16)u0.x; v[1] = (_Float16)u0.y;
        v[2] = (_Float16)u0.z; v[3] = (_Float16)u0.w;
        v[4] = (_Float16)u1.x; v[5] = (_Float16)u1.y;
        v[6] = (_Float16)u1.z; v[7] = (_Float16)u1.w;
        __builtin_nontemporal_store(v, (half8*)(xh + (size_t)e * 8));
    }
}

// ---------------------------------------------------------------------------
// aggregate v2 (x-space, R10 validated): one wave per dst node.  pass 1
// computes w=exp(leaky(a_s[sn]+a_d)) once per edge, staging {sn, w fp32x4};
// pass 2: per edge ONE u32 gather (lane's 2 f16 of x[sn], 256 B/row) + 8 fmac
// into z[4][2] f32.  Epilogue writes z[i] as f16 [4][128] for the final GEMM.
__global__ __launch_bounds__(256) void aggregate_kernel(
        const int* __restrict__ deg, const int* __restrict__ col2,
        const float4* __restrict__ as4, const float4* __restrict__ ad4,
        const unsigned int* __restrict__ xh32,
        unsigned int* __restrict__ z32) {
    __shared__ int    s_off[4][MAXDEG];
    __shared__ float4 s_w[4][MAXDEG];
    int tid = threadIdx.x;
    int wv = tid >> 6, lane = tid & 63;
    int i = (blockIdx.x * 256 + tid) >> 6;
    if (i >= N_DST) return;
    int dg = deg[i]; if (dg > MAXDEG) dg = MAXDEG;
    unsigned int* zo = z32 + (size_t)i * 256 + lane;   // u32 per lane per head
    if (dg == 0) {
        zo[0] = 0u; zo[64] = 0u; zo[128] = 0u; zo[192] = 0u;
        return;
    }
    float4 ad = ad4[i];
    const int* crow = col2 + i * MAXDEG;

    // pass 1: weights once, stage {src node, fp32 weights}
    float s0 = 0.f, s1 = 0.f, s2 = 0.f, s3 = 0.f;
    for (int e = lane; e < dg; e += 64) {
        int sn = crow[e];
        float4 av = as4[sn];
        float lx = av.x + ad.x; lx = lx > 0.f ? lx : 0.2f * lx;
        float ly = av.y + ad.y; ly = ly > 0.f ? ly : 0.2f * ly;
        float lz = av.z + ad.z; lz = lz > 0.f ? lz : 0.2f * lz;
        float lw = av.w + ad.w; lw = lw > 0.f ? lw : 0.2f * lw;
        float w0 = __expf(lx), w1 = __expf(ly), w2 = __expf(lz), w3 = __expf(lw);
        s0 += w0; s1 += w1; s2 += w2; s3 += w3;
        s_off[wv][e] = sn;
        s_w[wv][e] = (float4){w0, w1, w2, w3};
    }
    for (int off = 32; off >= 1; off >>= 1) {
        s0 += __shfl_xor(s0, off, 64);
        s1 += __shfl_xor(s1, off, 64);
        s2 += __shfl_xor(s2, off, 64);
        s3 += __shfl_xor(s3, off, 64);
    }
    float i0 = 0.25f / (s0 + 1e-16f);
    float i1 = 0.25f / (s1 + 1e-16f);
    float i2 = 0.25f / (s2 + 1e-16f);
    float i3 = 0.25f / (s3 + 1e-16f);

    // rescale in place (each lane rewrites its own entries)
    for (int e = lane; e < dg; e += 64) {
        float4 wf = s_w[wv][e];
        wf.x *= i0; wf.y *= i1; wf.z *= i2; wf.w *= i3;
        s_w[wv][e] = wf;
    }
    __asm__ volatile("s_waitcnt lgkmcnt(0)" ::: "memory");

    // pass 2: per edge 1 u32 gather + 8 fmac; unroll 4 (R9: wider is neutral)
    const unsigned int* xb = xh32 + lane;    // row = sn*64 u32
    float z00 = 0.f, z01 = 0.f, z10 = 0.f, z11 = 0.f;
    float z20 = 0.f, z21 = 0.f, z30 = 0.f, z31 = 0.f;
    int j = 0;
    for (; j + 4 <= dg; j += 4) {
        int sn0 = s_off[wv][j],     sn1 = s_off[wv][j + 1];
        int sn2 = s_off[wv][j + 2], sn3 = s_off[wv][j + 3];
        float4 w0 = s_w[wv][j],     w1 = s_w[wv][j + 1];
        float4 w2 = s_w[wv][j + 2], w3 = s_w[wv][j + 3];
        unsigned int g0 = xb[sn0 << 6];
        unsigned int g1 = xb[sn1 << 6];
        unsigned int g2 = xb[sn2 << 6];
        unsigned int g3 = xb[sn3 << 6];
        half2t hx;
        hx = bits2h(g0);
        { float xa = (float)hx[0], xc = (float)hx[1];
          z00 += w0.x * xa; z01 += w0.x * xc; z10 += w0.y * xa; z11 += w0.y * xc;
          z20 += w0.z * xa; z21 += w0.z * xc; z30 += w0.w * xa; z31 += w0.w * xc; }
        hx = bits2h(g1);
        { float xa = (float)hx[0], xc = (float)hx[1];
          z00 += w1.x * xa; z01 += w1.x * xc; z10 += w1.y * xa; z11 += w1.y * xc;
          z20 += w1.z * xa; z21 += w1.z * xc; z30 += w1.w * xa; z31 += w1.w * xc; }
        hx = bits2h(g2);
        { float xa = (float)hx[0], xc = (float)hx[1];
          z00 += w2.x * xa; z01 += w2.x * xc; z10 += w2.y * xa; z11 += w2.y * xc;
          z20 += w2.z * xa; z21 += w2.z * xc; z30 += w2.w * xa; z31 += w2.w * xc; }
        hx = bits2h(g3);
        { float xa = (float)hx[0], xc = (float)hx[1];
          z00 += w3.x * xa; z01 += w3.x * xc; z10 += w3.y * xa; z11 += w3.y * xc;
          z20 += w3.z * xa; z21 += w3.z * xc; z30 += w3.w * xa; z31 += w3.w * xc; }
    }
    for (; j < dg; ++j) {
        int sn0 = s_off[wv][j];
        float4 w0 = s_w[wv][j];
        unsigned int g0 = xb[sn0 << 6];
        half2t hx = bits2h(g0);
        float xa = (float)hx[0], xc = (float)hx[1];
        z00 += w0.x * xa; z01 += w0.x * xc; z10 += w0.y * xa; z11 += w0.y * xc;
        z20 += w0.z * xa; z21 += w0.z * xc; z30 += w0.w * xa; z31 += w0.w * xc;
    }
    // z[i][h][2*lane .. 2*lane+1] as f16; u32 slot = h*64 + lane
    zo[0]   = pack2h(z00, z01);
    zo[64]  = pack2h(z10, z11);
    zo[128] = pack2h(z20, z21);
    zo[192] = pack2h(z30, z31);
}

// ---------------------------------------------------------------------------
// final GEMM (R10 validated): out = z @ Wcat (+bias), z[n][512] f16.
// WfT (64 rows x 1024 B) staged once per block into LDS with XOR swizzle;
// 64 rows of z per block; per wave 4 col-tiles x 16 K-steps = 64 MFMA.
__global__ __launch_bounds__(256) void fgemm_kernel(
        const _Float16* __restrict__ z, const _Float16* __restrict__ WfT,
        const float* __restrict__ bias, float* __restrict__ out) {
    __shared__ _Float16 sW[64 * KTOT];   // 64 KB, swizzled
    int tid = threadIdx.x;
    {
        const float4* wsrc = (const float4*)WfT;
        #pragma unroll
        for (int it = 0; it < 16; ++it) {
            int idx = it * 256 + tid;
            int row = idx >> 6, slot = idx & 63;   // 64 float4 per 1024-B row
            float4 v = wsrc[idx];
            int byte_off = row * 1024 + ((slot * 16) ^ ((row & 7) << 4));
            *(float4*)((char*)sW + byte_off) = v;
        }
    }

    int w = tid >> 6, lane = tid & 63;
    int ll = lane & 15, q = lane >> 4;
    int rbase = blockIdx.x * 64 + w * 16;

    int arow = rbase + ll;
    if (arow >= N_DST) arow = N_DST - 1;           // clamp; stores guarded
    const _Float16* zr = z + (size_t)arow * KTOT + q * 8;
    half8 afrag[16];
    #pragma unroll
    for (int s = 0; s < 16; ++s)
        afrag[s] = *(const half8*)(zr + s * 32);

    f32x4 acc[4];
    #pragma unroll
    for (int t = 0; t < 4; ++t) acc[t] = (f32x4){0.f, 0.f, 0.f, 0.f};

    __syncthreads();
    int sw = (ll & 7) << 4;
    #pragma unroll
    for (int t = 0; t < 4; ++t) {
        const char* rowp = (const char*)sW + (t * 16 + ll) * 1024;
        f32x4 c = acc[t];
        #pragma unroll
        for (int s = 0; s < 16; ++s) {
            half8 bb = *(const half8*)(rowp + ((s * 64 + q * 16) ^ sw));
            c = __builtin_amdgcn_mfma_f32_16x16x32_f16(afrag[s], bb, c, 0, 0, 0);
        }
        acc[t] = c;
    }

    // C/D: reg r of tile t = (row=q*4+r, col=t*16+ll)
    #pragma unroll
    for (int t = 0; t < 4; ++t) {
        float bv = bias[t * 16 + ll];
        #pragma unroll
        for (int r = 0; r < 4; ++r) {
            int n = rbase + q * 4 + r;
            if (n < N_DST) out[(size_t)n * CDIM + t * 16 + ll] = acc[t][r] + bv;
        }
    }
}

// ---------------------------------------------------------------------------
extern "C" void kernel_launch(void* const* d_in, const int* in_sizes, int n_in,
                              void* d_out, int out_size, void* d_ws, size_t ws_size,
                              hipStream_t stream) {
    const float* x_src   = (const float*)d_in[0];
    const float* x_dst   = (const float*)d_in[1];
    const int*   ei      = (const int*)d_in[2];   // [2][E]: src then dst
    const float* W_src   = (const float*)d_in[3];
    const float* W_dst   = (const float*)d_in[4];
    const float* att_src = (const float*)d_in[5];
    const float* att_dst = (const float*)d_in[6];
    const float* bias    = (const float*)d_in[7];
    float* out = (float*)d_out;

    char* ws = (char*)d_ws;
    _Float16* xh   = (_Float16*)ws; ws += (size_t)N_SRC * IND * 2;      // 12.8 MB
    _Float16* z    = (_Float16*)ws; ws += (size_t)N_DST * KTOT * 2;     // 51.2 MB
    int*    col2   = (int*)ws;    ws += (size_t)N_DST * MAXDEG * 4;     // 19.2 MB
    float*  a_s    = (float*)ws;  ws += (size_t)N_SRC * 4 * 4;          // 800 KB
    float*  a_d    = (float*)ws;  ws += (size_t)N_DST * 4 * 4;          // 800 KB
    float*  WdA    = (float*)ws;  ws += 2048;
    float*  WsA    = (float*)ws;  ws += 2048;
    _Float16* WfT  = (_Float16*)ws; ws += (size_t)CDIM * KTOT * 2;      // 64 KB
    int*    deg    = (int*)ws;    ws += N_DST * 4;

    prep0_kernel<<<328, 256, 0, stream>>>(W_dst, att_dst, WdA,
                                          W_src, att_src, WsA, WfT, deg);
    big_kernel<<<NB_HIST2 + 2 * NB_G16 + NB_CAST, 256, 0, stream>>>(
            x_dst, WdA, a_d, x_src, WsA, a_s, xh,
            ei, ei + NEDGE, deg, col2);
    aggregate_kernel<<<(N_DST + 3) / 4, 256, 0, stream>>>(
            deg, col2, (const float4*)a_s, (const float4*)a_d,
            (const unsigned int*)xh, (unsigned int*)z);
    fgemm_kernel<<<(N_DST + 63) / 64, 256, 0, stream>>>(z, WfT, bias, out);
}

// Round 14
// 217.225 us; speedup vs baseline: 1.0341x; 1.0341x over previous
//
#include <hip/hip_runtime.h>
#include <hip/hip_bf16.h>

#define N_SRC 50000
#define N_DST 50000
#define NEDGE 800000
#define IND   128
#define HEADS 4
#define CDIM  64
#define HC    256   // HEADS*CDIM
#define KTOT  512   // HEADS*IND — final GEMM K
#define MAXDEG 96   // max in-degree; Binomial(800k,1/50k) max ~40, P(>96)~1e-22
#define HIST_GPB 256     // hist blocks per dst-range group
#define NB_HIST2 2048    // 8 groups * HIST_GPB
#define DPG 6250         // dst nodes per group (N_DST/8)
#define NB_G16 3125      // GEMV blocks per side (16 nodes/block)
#define NB_CAST 3125     // x_src f32->f16 cast blocks
// FINAL STATE (R14 = exact R11 revert, session best 218.2 us):
// R4: shared tail counters fatal (~500ns serialized same-address atomic).
// R5/R6/R8/R13: hist ~55-62 us across 5 structures — L2 transaction floor.
// R11: co-dispatching low-VGPR BW work (GEMV/cast) under the hist is ~free.
// R12: LDS-fusing the z GEMM into aggregate is neutral-to-worse.
// R13: NT hints on rider traffic REGRESS (+6 us; NT stores bypass L2 write-
// combining, WRITE 44.6->49 MB).  The +12 us over hist-floor is CU contention,
// not L2 pollution — accepted as part of the overlap bargain.
// R7: per-wave re-streamed weights = L2 bound; stage in LDS once/block.
// R9: random-gather kernels sit at the per-XCD COMPULSORY floor
// (FETCH = table x 8 XCDs; MLP-insensitive) -> only shrinking the table helps.
// R10: x-space aggregation (12.8 MB table) + post-GEMM; absmax 0.0039.
// R3: fp8 gather table fails accuracy (0.051 > 0.023) — f16 is the floor.

typedef _Float16 half8  __attribute__((ext_vector_type(8)));
typedef _Float16 half2t __attribute__((ext_vector_type(2)));
typedef float    f32x4  __attribute__((ext_vector_type(4)));
typedef int      i32x4  __attribute__((ext_vector_type(4)));

static __device__ __forceinline__ unsigned int pack2h(float a, float b) {
    union { half2t h; unsigned int u; } v;
    v.h[0] = (_Float16)a; v.h[1] = (_Float16)b;
    return v.u;
}
static __device__ __forceinline__ half2t bits2h(unsigned int u) {
    union { unsigned int u; half2t h; } v; v.u = u; return v.h;
}

// ---------------------------------------------------------------------------
// prep0: [0,196) zero deg; [196,198) fold W_dst·att_dst -> WdA[k*4+h];
// [198,200) fold W_src·att_src -> WsA; [200,328) WfT[c][h*128+k] f16.
__global__ void prep0_kernel(const float* __restrict__ Wdst,
                             const float* __restrict__ att_d,
                             float* __restrict__ WdA,
                             const float* __restrict__ Wsrc,
                             const float* __restrict__ att_s,
                             float* __restrict__ WsA,
                             _Float16* __restrict__ WfT,
                             int* __restrict__ deg) {
    int b = blockIdx.x, tid = threadIdx.x;
    if (b < 196) {
        int i = b * 256 + tid;
        if (i < N_DST) deg[i] = 0;
    } else if (b < 198) {
        int id = (b - 196) * 256 + tid;   // 0..511
        int k = id >> 2, h = id & 3;
        float acc = 0.f;
        for (int c = 0; c < CDIM; ++c)
            acc += Wdst[k * HC + h * CDIM + c] * att_d[h * CDIM + c];
        WdA[id] = acc;   // id == k*4+h
    } else if (b < 200) {
        int id = (b - 198) * 256 + tid;   // 0..511
        int k = id >> 2, h = id & 3;
        float acc = 0.f;
        for (int c = 0; c < CDIM; ++c)
            acc += Wsrc[k * HC + h * CDIM + c] * att_s[h * CDIM + c];
        WsA[id] = acc;
    } else {
        // WfT[c][hk]: c=0..63 out col, hk = h*128+k.  32768 elems.
        int idx = (b - 200) * 256 + tid;
        int c = idx >> 9, hk = idx & 511;
        int h = hk >> 7, k = hk & 127;
        WfT[idx] = (_Float16)Wsrc[k * HC + h * CDIM + c];
    }
}

// ---------------------------------------------------------------------------
// big (R11 validated): hist + GEMVs + cast co-dispatched.  hist ranks FIRST
// (transaction-bound, leaves BW/VALU idle); GEMV + cast (pure BW, VGPR 12-24)
// fill the idle pipes under it.  Plain (cached) rider accesses — R13 showed
// NT hints here regress.
__global__ __launch_bounds__(256) void big_kernel(
        const float* __restrict__ x_dst, const float* __restrict__ WdA,
        float* __restrict__ a_d,
        const float* __restrict__ x_src, const float* __restrict__ WsA,
        float* __restrict__ a_s,
        _Float16* __restrict__ xh,
        const int* __restrict__ src, const int* __restrict__ dst,
        int* __restrict__ deg, int* __restrict__ col2) {
    int b = blockIdx.x, tid = threadIdx.x;
    if (b < NB_HIST2) {
        int g  = b & 7;            // XCD-affine group
        int bg = b >> 3;           // 0..HIST_GPB-1 within group
        int lo = g * DPG, hi = lo + DPG;
        #pragma unroll 1
        for (int it = 0; it < 4; ++it) {
            int base = ((it * HIST_GPB + bg) << 10) + (tid << 2);
            if (base >= NEDGE) break;   // monotone in it; NEDGE%4==0, no straddle
            i32x4 dv = __builtin_nontemporal_load((const i32x4*)(dst + base));
            i32x4 sv = __builtin_nontemporal_load((const i32x4*)(src + base));
            #pragma unroll
            for (int j = 0; j < 4; ++j) {
                int d = dv[j];
                if (d >= lo && d < hi) {
                    int r = atomicAdd(&deg[d], 1);
                    if (r < MAXDEG) col2[d * MAXDEG + r] = sv[j];
                }
            }
        }
        return;
    }
    int rank = b - NB_HIST2;
    if (rank < 2 * NB_G16) {
        // ---- GEMV: 16 nodes/block (wave w: 4 nodes), folded 128x4 table ----
        const float* xbase; const float4* wa; float* outp; int which;
        if (rank < NB_G16) { xbase = x_dst; wa = (const float4*)WdA; outp = a_d; which = rank; }
        else               { xbase = x_src; wa = (const float4*)WsA; outp = a_s; which = rank - NB_G16; }
        int w = tid >> 6, lane = tid & 63;
        float4 wa0 = wa[lane], wa1 = wa[lane + 64];   // hoisted across 4 nodes
        int n0 = which * 16 + w * 4;
        #pragma unroll
        for (int p = 0; p < 4; ++p) {
            int n = n0 + p;
            const float* xp = xbase + (size_t)n * IND;
            float x0 = xp[lane], x1 = xp[lane + 64];
            float p0 = x0 * wa0.x + x1 * wa1.x;
            float p1 = x0 * wa0.y + x1 * wa1.y;
            float p2 = x0 * wa0.z + x1 * wa1.z;
            float p3 = x0 * wa0.w + x1 * wa1.w;
            for (int off = 32; off >= 1; off >>= 1) {
                p0 += __shfl_xor(p0, off, 64);
                p1 += __shfl_xor(p1, off, 64);
                p2 += __shfl_xor(p2, off, 64);
                p3 += __shfl_xor(p3, off, 64);
            }
            if (lane == 0) {
                outp[n * 4 + 0] = p0; outp[n * 4 + 1] = p1;
                outp[n * 4 + 2] = p2; outp[n * 4 + 3] = p3;
            }
        }
    } else {
        // ---- cast x_src -> xh f16, 8 elems/thread, fully coalesced ----
        int e = (rank - 2 * NB_G16) * 256 + tid;   // 0..799999, *8 elems
        const float* xp = x_src + (size_t)e * 8;
        float4 u0 = *(const float4*)(xp);
        float4 u1 = *(const float4*)(xp + 4);
        half8 v;
        v[0] = (_Float16)u0.x; v[1] = (_Float16)u0.y;
        v[2] = (_Float16)u0.z; v[3] = (_Float16)u0.w;
        v[4] = (_Float16)u1.x; v[5] = (_Float16)u1.y;
        v[6] = (_Float16)u1.z; v[7] = (_Float16)u1.w;
        *(half8*)(xh + (size_t)e * 8) = v;
    }
}

// ---------------------------------------------------------------------------
// aggregate v2 (x-space, R10 validated): one wave per dst node.  pass 1
// computes w=exp(leaky(a_s[sn]+a_d)) once per edge, staging {sn, w fp32x4};
// pass 2: per edge ONE u32 gather (lane's 2 f16 of x[sn], 256 B/row) + 8 fmac
// into z[4][2] f32.  Epilogue writes z[i] as f16 [4][128] for the final GEMM.
__global__ __launch_bounds__(256) void aggregate_kernel(
        const int* __restrict__ deg, const int* __restrict__ col2,
        const float4* __restrict__ as4, const float4* __restrict__ ad4,
        const unsigned int* __restrict__ xh32,
        unsigned int* __restrict__ z32) {
    __shared__ int    s_off[4][MAXDEG];
    __shared__ float4 s_w[4][MAXDEG];
    int tid = threadIdx.x;
    int wv = tid >> 6, lane = tid & 63;
    int i = (blockIdx.x * 256 + tid) >> 6;
    if (i >= N_DST) return;
    int dg = deg[i]; if (dg > MAXDEG) dg = MAXDEG;
    unsigned int* zo = z32 + (size_t)i * 256 + lane;   // u32 per lane per head
    if (dg == 0) {
        zo[0] = 0u; zo[64] = 0u; zo[128] = 0u; zo[192] = 0u;
        return;
    }
    float4 ad = ad4[i];
    const int* crow = col2 + i * MAXDEG;

    // pass 1: weights once, stage {src node, fp32 weights}
    float s0 = 0.f, s1 = 0.f, s2 = 0.f, s3 = 0.f;
    for (int e = lane; e < dg; e += 64) {
        int sn = crow[e];
        float4 av = as4[sn];
        float lx = av.x + ad.x; lx = lx > 0.f ? lx : 0.2f * lx;
        float ly = av.y + ad.y; ly = ly > 0.f ? ly : 0.2f * ly;
        float lz = av.z + ad.z; lz = lz > 0.f ? lz : 0.2f * lz;
        float lw = av.w + ad.w; lw = lw > 0.f ? lw : 0.2f * lw;
        float w0 = __expf(lx), w1 = __expf(ly), w2 = __expf(lz), w3 = __expf(lw);
        s0 += w0; s1 += w1; s2 += w2; s3 += w3;
        s_off[wv][e] = sn;
        s_w[wv][e] = (float4){w0, w1, w2, w3};
    }
    for (int off = 32; off >= 1; off >>= 1) {
        s0 += __shfl_xor(s0, off, 64);
        s1 += __shfl_xor(s1, off, 64);
        s2 += __shfl_xor(s2, off, 64);
        s3 += __shfl_xor(s3, off, 64);
    }
    float i0 = 0.25f / (s0 + 1e-16f);
    float i1 = 0.25f / (s1 + 1e-16f);
    float i2 = 0.25f / (s2 + 1e-16f);
    float i3 = 0.25f / (s3 + 1e-16f);

    // rescale in place (each lane rewrites its own entries)
    for (int e = lane; e < dg; e += 64) {
        float4 wf = s_w[wv][e];
        wf.x *= i0; wf.y *= i1; wf.z *= i2; wf.w *= i3;
        s_w[wv][e] = wf;
    }
    __asm__ volatile("s_waitcnt lgkmcnt(0)" ::: "memory");

    // pass 2: per edge 1 u32 gather + 8 fmac; unroll 4 (R9: wider is neutral)
    const unsigned int* xb = xh32 + lane;    // row = sn*64 u32
    float z00 = 0.f, z01 = 0.f, z10 = 0.f, z11 = 0.f;
    float z20 = 0.f, z21 = 0.f, z30 = 0.f, z31 = 0.f;
    int j = 0;
    for (; j + 4 <= dg; j += 4) {
        int sn0 = s_off[wv][j],     sn1 = s_off[wv][j + 1];
        int sn2 = s_off[wv][j + 2], sn3 = s_off[wv][j + 3];
        float4 w0 = s_w[wv][j],     w1 = s_w[wv][j + 1];
        float4 w2 = s_w[wv][j + 2], w3 = s_w[wv][j + 3];
        unsigned int g0 = xb[sn0 << 6];
        unsigned int g1 = xb[sn1 << 6];
        unsigned int g2 = xb[sn2 << 6];
        unsigned int g3 = xb[sn3 << 6];
        half2t hx;
        hx = bits2h(g0);
        { float xa = (float)hx[0], xc = (float)hx[1];
          z00 += w0.x * xa; z01 += w0.x * xc; z10 += w0.y * xa; z11 += w0.y * xc;
          z20 += w0.z * xa; z21 += w0.z * xc; z30 += w0.w * xa; z31 += w0.w * xc; }
        hx = bits2h(g1);
        { float xa = (float)hx[0], xc = (float)hx[1];
          z00 += w1.x * xa; z01 += w1.x * xc; z10 += w1.y * xa; z11 += w1.y * xc;
          z20 += w1.z * xa; z21 += w1.z * xc; z30 += w1.w * xa; z31 += w1.w * xc; }
        hx = bits2h(g2);
        { float xa = (float)hx[0], xc = (float)hx[1];
          z00 += w2.x * xa; z01 += w2.x * xc; z10 += w2.y * xa; z11 += w2.y * xc;
          z20 += w2.z * xa; z21 += w2.z * xc; z30 += w2.w * xa; z31 += w2.w * xc; }
        hx = bits2h(g3);
        { float xa = (float)hx[0], xc = (float)hx[1];
          z00 += w3.x * xa; z01 += w3.x * xc; z10 += w3.y * xa; z11 += w3.y * xc;
          z20 += w3.z * xa; z21 += w3.z * xc; z30 += w3.w * xa; z31 += w3.w * xc; }
    }
    for (; j < dg; ++j) {
        int sn0 = s_off[wv][j];
        float4 w0 = s_w[wv][j];
        unsigned int g0 = xb[sn0 << 6];
        half2t hx = bits2h(g0);
        float xa = (float)hx[0], xc = (float)hx[1];
        z00 += w0.x * xa; z01 += w0.x * xc; z10 += w0.y * xa; z11 += w0.y * xc;
        z20 += w0.z * xa; z21 += w0.z * xc; z30 += w0.w * xa; z31 += w0.w * xc;
    }
    // z[i][h][2*lane .. 2*lane+1] as f16; u32 slot = h*64 + lane
    zo[0]   = pack2h(z00, z01);
    zo[64]  = pack2h(z10, z11);
    zo[128] = pack2h(z20, z21);
    zo[192] = pack2h(z30, z31);
}

// ---------------------------------------------------------------------------
// final GEMM (R10 validated): out = z @ Wcat (+bias), z[n][512] f16.
// WfT (64 rows x 1024 B) staged once per block into LDS with XOR swizzle;
// 64 rows of z per block; per wave 4 col-tiles x 16 K-steps = 64 MFMA.
__global__ __launch_bounds__(256) void fgemm_kernel(
        const _Float16* __restrict__ z, const _Float16* __restrict__ WfT,
        const float* __restrict__ bias, float* __restrict__ out) {
    __shared__ _Float16 sW[64 * KTOT];   // 64 KB, swizzled
    int tid = threadIdx.x;
    {
        const float4* wsrc = (const float4*)WfT;
        #pragma unroll
        for (int it = 0; it < 16; ++it) {
            int idx = it * 256 + tid;
            int row = idx >> 6, slot = idx & 63;   // 64 float4 per 1024-B row
            float4 v = wsrc[idx];
            int byte_off = row * 1024 + ((slot * 16) ^ ((row & 7) << 4));
            *(float4*)((char*)sW + byte_off) = v;
        }
    }

    int w = tid >> 6, lane = tid & 63;
    int ll = lane & 15, q = lane >> 4;
    int rbase = blockIdx.x * 64 + w * 16;

    int arow = rbase + ll;
    if (arow >= N_DST) arow = N_DST - 1;           // clamp; stores guarded
    const _Float16* zr = z + (size_t)arow * KTOT + q * 8;
    half8 afrag[16];
    #pragma unroll
    for (int s = 0; s < 16; ++s)
        afrag[s] = *(const half8*)(zr + s * 32);

    f32x4 acc[4];
    #pragma unroll
    for (int t = 0; t < 4; ++t) acc[t] = (f32x4){0.f, 0.f, 0.f, 0.f};

    __syncthreads();
    int sw = (ll & 7) << 4;
    #pragma unroll
    for (int t = 0; t < 4; ++t) {
        const char* rowp = (const char*)sW + (t * 16 + ll) * 1024;
        f32x4 c = acc[t];
        #pragma unroll
        for (int s = 0; s < 16; ++s) {
            half8 bb = *(const half8*)(rowp + ((s * 64 + q * 16) ^ sw));
            c = __builtin_amdgcn_mfma_f32_16x16x32_f16(afrag[s], bb, c, 0, 0, 0);
        }
        acc[t] = c;
    }

    // C/D: reg r of tile t = (row=q*4+r, col=t*16+ll)
    #pragma unroll
    for (int t = 0; t < 4; ++t) {
        float bv = bias[t * 16 + ll];
        #pragma unroll
        for (int r = 0; r < 4; ++r) {
            int n = rbase + q * 4 + r;
            if (n < N_DST) out[(size_t)n * CDIM + t * 16 + ll] = acc[t][r] + bv;
        }
    }
}

// ---------------------------------------------------------------------------
extern "C" void kernel_launch(void* const* d_in, const int* in_sizes, int n_in,
                              void* d_out, int out_size, void* d_ws, size_t ws_size,
                              hipStream_t stream) {
    const float* x_src   = (const float*)d_in[0];
    const float* x_dst   = (const float*)d_in[1];
    const int*   ei      = (const int*)d_in[2];   // [2][E]: src then dst
    const float* W_src   = (const float*)d_in[3];
    const float* W_dst   = (const float*)d_in[4];
    const float* att_src = (const float*)d_in[5];
    const float* att_dst = (const float*)d_in[6];
    const float* bias    = (const float*)d_in[7];
    float* out = (float*)d_out;

    char* ws = (char*)d_ws;
    _Float16* xh   = (_Float16*)ws; ws += (size_t)N_SRC * IND * 2;      // 12.8 MB
    _Float16* z    = (_Float16*)ws; ws += (size_t)N_DST * KTOT * 2;     // 51.2 MB
    int*    col2   = (int*)ws;    ws += (size_t)N_DST * MAXDEG * 4;     // 19.2 MB
    float*  a_s    = (float*)ws;  ws += (size_t)N_SRC * 4 * 4;          // 800 KB
    float*  a_d    = (float*)ws;  ws += (size_t)N_DST * 4 * 4;          // 800 KB
    float*  WdA    = (float*)ws;  ws += 2048;
    float*  WsA    = (float*)ws;  ws += 2048;
    _Float16* WfT  = (_Float16*)ws; ws += (size_t)CDIM * KTOT * 2;      // 64 KB
    int*    deg    = (int*)ws;    ws += N_DST * 4;

    prep0_kernel<<<328, 256, 0, stream>>>(W_dst, att_dst, WdA,
                                          W_src, att_src, WsA, WfT, deg);
    big_kernel<<<NB_HIST2 + 2 * NB_G16 + NB_CAST, 256, 0, stream>>>(
            x_dst, WdA, a_d, x_src, WsA, a_s, xh,
            ei, ei + NEDGE, deg, col2);
    aggregate_kernel<<<(N_DST + 3) / 4, 256, 0, stream>>>(
            deg, col2, (const float4*)a_s, (const float4*)a_d,
            (const unsigned int*)xh, (unsigned int*)z);
    fgemm_kernel<<<(N_DST + 63) / 64, 256, 0, stream>>>(z, WfT, bias, out);
}